// Round 7
// baseline (676.088 us; speedup 1.0000x reference)
//
#include <hip/hip_runtime.h>
#include <hip/hip_bf16.h>
#include <cstdint>
#include <cstddef>

#define KD 512

// ---- workspace byte offsets ----
#define OFF_CN   0u           // 4096 f32 coarse codebook norms
#define OFF_FN   16384u       // 8192 f32 fine codebook norms
#define OFF_ZN   49152u       // 8192 f32 z-coarse row norms
#define OFF_RN   81920u       // 8192 f32 residual row norms
#define OFF_LOSS 114688u      // 1 f32 loss accumulator
#define OFF_AMC  114944u      // 8192 u64 coarse argmin keys
#define OFF_AMF  180480u      // 8192 u64 fine argmin keys
#define OFF_CEH  246016u      // 4096x512 bf16 coarse emb hi (FRAG layout)
#define OFF_CEL  4440320u     // 4096x512 bf16 coarse emb lo (FRAG layout)
#define OFF_FEH  8634624u     // 8192x512 bf16 fine emb hi (FRAG layout)
#define OFF_FEL  17023232u    // 8192x512 bf16 fine emb lo (FRAG layout)
#define OFF_ZCH  25411840u    // 8192x512 bf16 z-coarse hi (row-major)
#define OFF_ZCL  33800448u
#define OFF_RH   42189056u    // 8192x512 bf16 residual hi (row-major)
#define OFF_RL   50577664u
#define OFF_W1H  58966272u    // 512x512 bf16 w_c2f hi (FRAG layout)
#define OFF_W1L  59490560u
#define OFF_W2H  60014848u
#define OFF_W2L  60539136u
#define OFF_H    61063424u    // 8192x512 f32
#define OFF_INFL 77840640u    // 8192x512 bf16
// total = 86,229,248 bytes

// frag layout: 16B chunk index = ((row>>4)*16 + (k>>5))*64 + lane,
// lane = (row&15) | (((k>>3)&3)<<4); chunk holds elems k..k+7 of row.

typedef __attribute__((ext_vector_type(8))) short bf16x8;
typedef __attribute__((ext_vector_type(4))) float f32x4;

__device__ __forceinline__ bf16x8 as_bf16x8(int4 v) {
  union { int4 i; bf16x8 b; } u; u.i = v; return u.b;
}

__device__ __forceinline__ float block_sum(float v, float* sred) {
#pragma unroll
  for (int off = 32; off > 0; off >>= 1) v += __shfl_down(v, off, 64);
  if ((threadIdx.x & 63) == 0) sred[threadIdx.x >> 6] = v;
  __syncthreads();
  float r = sred[0] + sred[1] + sred[2] + sred[3];
  __syncthreads();
  return r;
}

__device__ __forceinline__ float sigmoidf_(float x) { return 1.0f / (1.0f + expf(-x)); }

__device__ __forceinline__ void split_bf16(float v, __hip_bfloat16* hi, __hip_bfloat16* lo) {
  __hip_bfloat16 h = __float2bfloat16(v);
  *hi = h;
  *lo = __float2bfloat16(v - __bfloat162float(h));
}

// ---- prep: 4 rows/block, wave = one row. Codebooks+weights -> FRAG; zc -> rm ----
// blocks [0,3072): ce(4096)+fe(8192) rows; [3072,5120): zc rows; [5120,5376): w rows
__global__ __launch_bounds__(256) void prep(
    const float* __restrict__ ce, const float* __restrict__ fe, const float* __restrict__ z,
    const float* __restrict__ w1, const float* __restrict__ w2,
    float* __restrict__ cn, float* __restrict__ fn, float* __restrict__ zn,
    __hip_bfloat16* __restrict__ ceH, __hip_bfloat16* __restrict__ ceL,
    __hip_bfloat16* __restrict__ feH, __hip_bfloat16* __restrict__ feL,
    __hip_bfloat16* __restrict__ zcH, __hip_bfloat16* __restrict__ zcL,
    __hip_bfloat16* __restrict__ w1H, __hip_bfloat16* __restrict__ w1L,
    __hip_bfloat16* __restrict__ w2H, __hip_bfloat16* __restrict__ w2L,
    float* __restrict__ lossp) {
  const int b = blockIdx.x, t = threadIdx.x;
  const int sub = t >> 6;   // row within block
  const int L = t & 63;     // lane: elems [8L, 8L+8)
  union { int4 i; __hip_bfloat16 s[8]; } ph, pl;
  float acc = 0.0f;

  if (b < 3072) {  // codebooks -> frag
    int r = 4 * b + sub;
    const float* src;
    __hip_bfloat16 *dh, *dl;
    float* np_;
    int row;
    if (r < 4096) { row = r; src = ce + (size_t)row * KD; dh = ceH; dl = ceL; np_ = cn + row; }
    else { row = r - 4096; src = fe + (size_t)row * KD; dh = feH; dl = feL; np_ = fn + row; }
    float4 v0 = *(const float4*)(src + 8 * L);
    float4 v1 = *(const float4*)(src + 8 * L + 4);
    float vv[8] = {v0.x, v0.y, v0.z, v0.w, v1.x, v1.y, v1.z, v1.w};
#pragma unroll
    for (int j = 0; j < 8; ++j) { acc += vv[j] * vv[j]; split_bf16(vv[j], &ph.s[j], &pl.s[j]); }
    const int ci = ((row >> 4) * 16 + (L >> 2)) * 64 + ((L & 3) << 4) + (row & 15);
    ((int4*)dh)[ci] = ph.i;
    ((int4*)dl)[ci] = pl.i;
#pragma unroll
    for (int off = 32; off > 0; off >>= 1) acc += __shfl_down(acc, off, 64);
    if (L == 0) np_[0] = acc;
  } else if (b < 5120) {  // z-coarse -> row-major
    int r = 4 * (b - 3072) + sub;
    const float* src = z + (size_t)r * 1024;
    float4 v0 = *(const float4*)(src + 8 * L);
    float4 v1 = *(const float4*)(src + 8 * L + 4);
    float vv[8] = {v0.x, v0.y, v0.z, v0.w, v1.x, v1.y, v1.z, v1.w};
#pragma unroll
    for (int j = 0; j < 8; ++j) { acc += vv[j] * vv[j]; split_bf16(vv[j], &ph.s[j], &pl.s[j]); }
    ((int4*)zcH)[(size_t)r * 64 + L] = ph.i;
    ((int4*)zcL)[(size_t)r * 64 + L] = pl.i;
#pragma unroll
    for (int off = 32; off > 0; off >>= 1) acc += __shfl_down(acc, off, 64);
    if (L == 0) zn[r] = acc;
  } else {  // weights -> frag
    int r = 4 * (b - 5120) + sub;
    const float* src;
    __hip_bfloat16 *dh, *dl;
    int row;
    if (r < 512) { row = r; src = w1 + (size_t)row * KD; dh = w1H; dl = w1L; }
    else { row = r - 512; src = w2 + (size_t)row * KD; dh = w2H; dl = w2L; }
    float4 v0 = *(const float4*)(src + 8 * L);
    float4 v1 = *(const float4*)(src + 8 * L + 4);
    float vv[8] = {v0.x, v0.y, v0.z, v0.w, v1.x, v1.y, v1.z, v1.w};
#pragma unroll
    for (int j = 0; j < 8; ++j) split_bf16(vv[j], &ph.s[j], &pl.s[j]);
    const int ci = ((row >> 4) * 16 + (L >> 2)) * 64 + ((L & 3) << 4) + (row & 15);
    ((int4*)dh)[ci] = ph.i;
    ((int4*)dl)[ci] = pl.i;
    if (b == 5120 && t == 0) lossp[0] = 0.0f;
  }
}

// ---- vq7: 256 codes x 128 queries/block; 4 waves own disjoint 64-code strips ----
// A = codebook (frag, direct global, unique per wave), B = queries (LDS dbuf).
// dot3 = Ah*Bh + Ah*Bl + Al*Bh. Per-query argmin -> atomicMin u64 key.
__global__ __launch_bounds__(256) void vq7(
    const int4* __restrict__ AfH, const int4* __restrict__ AfL,
    const __hip_bfloat16* __restrict__ Bh, const __hip_bfloat16* __restrict__ Bl,
    const float* __restrict__ qn, const float* __restrict__ cn,
    unsigned long long* __restrict__ amin) {
  __shared__ __align__(16) __hip_bfloat16 sBh[2][128 * 32];
  __shared__ __align__(16) __hip_bfloat16 sBl[2][128 * 32];
  const int t = threadIdx.x, w = t >> 6, l = t & 63;
  const int colTile = blockIdx.x << 7;                 // 128 queries
  const int codeBase = (blockIdx.y << 8) + (w << 6);   // this wave's 64 codes

  // B staging: thread covers query rows srow, srow+64; 16B block sb (swizzled)
  const int srow = t >> 2, sb = t & 3;
  const int skE = sb << 3;
  const int swz = (sb ^ ((srow >> 1) & 3)) << 3;
  const int wOff0 = (srow << 5) + swz;
  const int wOff1 = ((srow + 64) << 5) + swz;
  const size_t br0 = (size_t)(colTile + srow) * KD;
  const size_t br1 = (size_t)(colTile + 64 + srow) * KD;

  const int fr = l & 15, q = l >> 4;

  int aB[4];
#pragma unroll
  for (int mt = 0; mt < 4; ++mt) aB[mt] = ((codeBase >> 4) + mt) * 1024 + l;

  f32x4 acc[4][8];
#pragma unroll
  for (int i = 0; i < 4; ++i)
#pragma unroll
    for (int j = 0; j < 8; ++j) acc[i][j] = (f32x4){0.f, 0.f, 0.f, 0.f};

  // prologue: chunk 0
  int4 rBh0 = *(const int4*)(Bh + br0 + skE);
  int4 rBh1 = *(const int4*)(Bh + br1 + skE);
  int4 rBl0 = *(const int4*)(Bl + br0 + skE);
  int4 rBl1 = *(const int4*)(Bl + br1 + skE);
  int4 aH[4], aL[4];
#pragma unroll
  for (int mt = 0; mt < 4; ++mt) { aH[mt] = AfH[aB[mt]]; aL[mt] = AfL[aB[mt]]; }

  int p = 0;
  for (int kk = 0; kk < KD; kk += 32) {
    *(int4*)(sBh[p] + wOff0) = rBh0; *(int4*)(sBh[p] + wOff1) = rBh1;
    *(int4*)(sBl[p] + wOff0) = rBl0; *(int4*)(sBl[p] + wOff1) = rBl1;
    __syncthreads();  // single barrier per chunk (dbuf)

    bf16x8 afh[4], afl[4];
#pragma unroll
    for (int mt = 0; mt < 4; ++mt) { afh[mt] = as_bf16x8(aH[mt]); afl[mt] = as_bf16x8(aL[mt]); }

    const int nkc = (kk + 32 < KD) ? ((kk >> 5) + 1) : 0;
    const int nkE = nkc << 5;
    rBh0 = *(const int4*)(Bh + br0 + nkE + skE);
    rBh1 = *(const int4*)(Bh + br1 + nkE + skE);
    rBl0 = *(const int4*)(Bl + br0 + nkE + skE);
    rBl1 = *(const int4*)(Bl + br1 + nkE + skE);
#pragma unroll
    for (int mt = 0; mt < 4; ++mt) {
      aH[mt] = AfH[aB[mt] + (nkc << 6)];
      aL[mt] = AfL[aB[mt] + (nkc << 6)];
    }

    // per-nt: read B frags then consume immediately (small live range)
#pragma unroll
    for (int nt = 0; nt < 8; ++nt) {
      const int rB = (nt << 4) + fr;
      const int o = (rB << 5) + ((q ^ ((rB >> 1) & 3)) << 3);
      bf16x8 bfh = *(const bf16x8*)(sBh[p] + o);
      bf16x8 bfl = *(const bf16x8*)(sBl[p] + o);
#pragma unroll
      for (int mt = 0; mt < 4; ++mt) {
        acc[mt][nt] = __builtin_amdgcn_mfma_f32_16x16x32_bf16(afh[mt], bfh, acc[mt][nt], 0, 0, 0);
        acc[mt][nt] = __builtin_amdgcn_mfma_f32_16x16x32_bf16(afh[mt], bfl, acc[mt][nt], 0, 0, 0);
        acc[mt][nt] = __builtin_amdgcn_mfma_f32_16x16x32_bf16(afl[mt], bfh, acc[mt][nt], 0, 0, 0);
      }
    }
    p ^= 1;
  }

  // epilogue: per-query argmin. C/D: col(query) = lane&15, row(code) = q*4+reg
#pragma unroll
  for (int nt = 0; nt < 8; ++nt) {
    const int query = colTile + (nt << 4) + fr;
    const float xn = qn[query];
    unsigned long long key = ~0ULL;
#pragma unroll
    for (int mt = 0; mt < 4; ++mt) {
#pragma unroll
      for (int reg = 0; reg < 4; ++reg) {
        const int code = codeBase + (mt << 4) + (q << 2) + reg;
        float d = (xn + cn[code]) - 2.0f * acc[mt][nt][reg];
        unsigned ub = __float_as_uint(d);
        ub = (ub & 0x80000000u) ? ~ub : (ub | 0x80000000u);
        unsigned long long k2 = ((unsigned long long)ub << 32) | (unsigned long long)(unsigned)code;
        if (k2 < key) key = k2;
      }
    }
    unsigned long long o1 = __shfl_xor(key, 16, 64);
    if (o1 < key) key = o1;
    unsigned long long o2 = __shfl_xor(key, 32, 64);
    if (o2 < key) key = o2;
    if (l < 16) atomicMin(amin + colTile + (nt << 4) + l, key);
  }
}

// ---- mlp7: A = gathered codes (LDS dbuf from frag codebook), B = weights frag ----
// 128 samples x 128 outdims per block; waves 2x2 (64x64 each).
__global__ __launch_bounds__(256) void mlp7(
    const int4* __restrict__ AfH, const int4* __restrict__ AfL,
    const unsigned long long* __restrict__ gather,
    const int4* __restrict__ WfH, const int4* __restrict__ WfL,
    const float* __restrict__ bias, float* __restrict__ C) {
  __shared__ __align__(16) __hip_bfloat16 sAh[2][128 * 32];
  __shared__ __align__(16) __hip_bfloat16 sAl[2][128 * 32];
  const int t = threadIdx.x, w = t >> 6, l = t & 63;
  const int rowTile = blockIdx.y << 7;
  const int colTile = blockIdx.x << 7;
  const int wr = (w >> 1) << 6;
  const int wc = (w & 1) << 6;

  const int srow = t >> 2, sb = t & 3;
  const int swz = (sb ^ ((srow >> 1) & 3)) << 3;
  const int wOff0 = (srow << 5) + swz;
  const int wOff1 = ((srow + 64) << 5) + swz;
  const unsigned i0 = ((const unsigned*)gather)[2 * (rowTile + srow)];
  const unsigned i1 = ((const unsigned*)gather)[2 * (rowTile + 64 + srow)];
  const int a0 = (int)((i0 >> 4) * 1024) + (sb << 4) + (int)(i0 & 15);
  const int a1 = (int)((i1 >> 4) * 1024) + (sb << 4) + (int)(i1 & 15);

  const int fr = l & 15, q = l >> 4;

  int bB[4];
#pragma unroll
  for (int nt = 0; nt < 4; ++nt) bB[nt] = (((colTile + wc) >> 4) + nt) * 1024 + l;

  f32x4 acc[4][4];
#pragma unroll
  for (int i = 0; i < 4; ++i)
#pragma unroll
    for (int j = 0; j < 4; ++j) acc[i][j] = (f32x4){0.f, 0.f, 0.f, 0.f};

  // prologue
  int4 rAh0 = AfH[a0], rAh1 = AfH[a1], rAl0 = AfL[a0], rAl1 = AfL[a1];
  int4 bH[4], bL[4];
#pragma unroll
  for (int nt = 0; nt < 4; ++nt) { bH[nt] = WfH[bB[nt]]; bL[nt] = WfL[bB[nt]]; }

  int p = 0;
  for (int kk = 0; kk < KD; kk += 32) {
    *(int4*)(sAh[p] + wOff0) = rAh0; *(int4*)(sAh[p] + wOff1) = rAh1;
    *(int4*)(sAl[p] + wOff0) = rAl0; *(int4*)(sAl[p] + wOff1) = rAl1;
    __syncthreads();

    bf16x8 bfh[4], bfl[4];
#pragma unroll
    for (int nt = 0; nt < 4; ++nt) { bfh[nt] = as_bf16x8(bH[nt]); bfl[nt] = as_bf16x8(bL[nt]); }

    const int nkc = (kk + 32 < KD) ? ((kk >> 5) + 1) : 0;
    rAh0 = AfH[a0 + nkc * 64]; rAh1 = AfH[a1 + nkc * 64];
    rAl0 = AfL[a0 + nkc * 64]; rAl1 = AfL[a1 + nkc * 64];
#pragma unroll
    for (int nt = 0; nt < 4; ++nt) {
      bH[nt] = WfH[bB[nt] + (nkc << 6)];
      bL[nt] = WfL[bB[nt] + (nkc << 6)];
    }

#pragma unroll
    for (int mt = 0; mt < 4; ++mt) {
      const int rA = wr + (mt << 4) + fr;
      const int o = (rA << 5) + ((q ^ ((rA >> 1) & 3)) << 3);
      bf16x8 afh = *(const bf16x8*)(sAh[p] + o);
      bf16x8 afl = *(const bf16x8*)(sAl[p] + o);
#pragma unroll
      for (int nt = 0; nt < 4; ++nt) {
        acc[mt][nt] = __builtin_amdgcn_mfma_f32_16x16x32_bf16(afh, bfh[nt], acc[mt][nt], 0, 0, 0);
        acc[mt][nt] = __builtin_amdgcn_mfma_f32_16x16x32_bf16(afh, bfl[nt], acc[mt][nt], 0, 0, 0);
        acc[mt][nt] = __builtin_amdgcn_mfma_f32_16x16x32_bf16(afl, bfh[nt], acc[mt][nt], 0, 0, 0);
      }
    }
    p ^= 1;
  }

  const int quad = l >> 4;
#pragma unroll
  for (int mt = 0; mt < 4; ++mt) {
#pragma unroll
    for (int reg = 0; reg < 4; ++reg) {
      const int row = rowTile + wr + (mt << 4) + (quad << 2) + reg;
#pragma unroll
      for (int nt = 0; nt < 4; ++nt) {
        const int col = colTile + wc + (nt << 4) + fr;
        C[(size_t)row * KD + col] = acc[mt][nt][reg] + bias[col];
      }
    }
  }
}

// ---- LN + leaky -> influence(bf16); residual hi/lo (row-major) + norms ----
__global__ __launch_bounds__(256) void ln_residual(
    const float* __restrict__ h, const float* __restrict__ g, const float* __restrict__ be,
    const float* __restrict__ z, const float* __restrict__ gRaw,
    __hip_bfloat16* __restrict__ infl, float* __restrict__ rn,
    __hip_bfloat16* __restrict__ rH, __hip_bfloat16* __restrict__ rL) {
  __shared__ float sred[4];
  const int row = blockIdx.x, t = threadIdx.x;
  const size_t base = (size_t)row * KD;
  float h0 = h[base + t], h1 = h[base + t + 256];
  float m = block_sum(h0 + h1, sred) * (1.0f / 512.0f);
  float d0 = h0 - m, d1 = h1 - m;
  float var = block_sum(d0 * d0 + d1 * d1, sred) * (1.0f / 512.0f);
  float sq = sqrtf(var + 1e-5f);
  float gc = sigmoidf_(gRaw[0]);
  float v0 = d0 / sq * g[t] + be[t];
  float v1 = d1 / sq * g[t + 256] + be[t + 256];
  v0 = v0 > 0.0f ? v0 : 0.1f * v0;
  v1 = v1 > 0.0f ? v1 : 0.1f * v1;
  infl[base + t] = __float2bfloat16(v0);
  infl[base + t + 256] = __float2bfloat16(v1);
  float zf0 = z[(size_t)row * 1024 + 512 + t];
  float zf1 = z[(size_t)row * 1024 + 512 + t + 256];
  float r0 = zf0 - gc * v0, r1 = zf1 - gc * v1;
  __hip_bfloat16 hh, ll;
  split_bf16(r0, &hh, &ll);
  rH[base + t] = hh; rL[base + t] = ll;
  split_bf16(r1, &hh, &ll);
  rH[base + t + 256] = hh; rL[base + t + 256] = ll;
  float rs = block_sum(r0 * r0 + r1 * r1, sred);
  if (t == 0) rn[row] = rs;
}

// ---- LN+leaky on h2, gather q_c/q_f, outputs + loss partials ----
__global__ __launch_bounds__(256) void finalize(
    const float* __restrict__ h, const float* __restrict__ g, const float* __restrict__ be,
    const __hip_bfloat16* __restrict__ infl,
    const unsigned long long* __restrict__ amc, const unsigned long long* __restrict__ amf,
    const float* __restrict__ z, const float* __restrict__ ce, const float* __restrict__ fe,
    const float* __restrict__ gcRaw, const float* __restrict__ gfRaw,
    float* __restrict__ out, float* __restrict__ lossp) {
  __shared__ float sred[4];
  const int row = blockIdx.x, t = threadIdx.x;
  const size_t base = (size_t)row * KD;
  float h0 = h[base + t], h1 = h[base + t + 256];
  float m = block_sum(h0 + h1, sred) * (1.0f / 512.0f);
  float d0 = h0 - m, d1 = h1 - m;
  float var = block_sum(d0 * d0 + d1 * d1, sred) * (1.0f / 512.0f);
  float sq = sqrtf(var + 1e-5f);
  float fb0 = d0 / sq * g[t] + be[t];
  float fb1 = d1 / sq * g[t + 256] + be[t + 256];
  fb0 = fb0 > 0.0f ? fb0 : 0.1f * fb0;
  fb1 = fb1 > 0.0f ? fb1 : 0.1f * fb1;
  float gc = sigmoidf_(gcRaw[0]);
  float gf = sigmoidf_(gfRaw[0]);
  unsigned ic = (unsigned)(amc[row] & 0xffffffffULL);
  unsigned ifx = (unsigned)(amf[row] & 0xffffffffULL);
  float loc = 0.0f;
#pragma unroll
  for (int j = 0; j < 2; ++j) {
    int c = t + j * 256;
    float fb = j ? fb1 : fb0;
    float qc = ce[(size_t)ic * KD + c];
    float qf = fe[(size_t)ifx * KD + c];
    float zc = z[(size_t)row * 1024 + c];
    float zf = z[(size_t)row * 1024 + 512 + c];
    float fl = __bfloat162float(infl[base + c]);
    out[(size_t)row * 1024 + c] = qc + 0.1f * gf * fb;
    out[(size_t)row * 1024 + 512 + c] = qf + gc * fl;
    float dc = qc - zc;
    float res = zf - gc * fl;
    float df = qf - res;
    loc += dc * dc + df * df;
  }
  float ls = block_sum(loc, sred);
  if (t == 0) atomicAdd(lossp, ls);
}

__global__ void loss_write(const float* __restrict__ lossp, float* __restrict__ out) {
  out[0] = 1.25f * lossp[0] / (8192.0f * 512.0f);
}

extern "C" void kernel_launch(void* const* d_in, const int* in_sizes, int n_in,
                              void* d_out, int out_size, void* d_ws, size_t ws_size,
                              hipStream_t stream) {
  const float* z      = (const float*)d_in[0];
  const float* ce     = (const float*)d_in[1];
  const float* fe     = (const float*)d_in[2];
  const float* w_c2f  = (const float*)d_in[3];
  const float* b_c2f  = (const float*)d_in[4];
  const float* g_c2f  = (const float*)d_in[5];
  const float* be_c2f = (const float*)d_in[6];
  const float* w_f2c  = (const float*)d_in[7];
  const float* b_f2c  = (const float*)d_in[8];
  const float* g_f2c  = (const float*)d_in[9];
  const float* be_f2c = (const float*)d_in[10];
  const float* gcRaw  = (const float*)d_in[11];
  const float* gfRaw  = (const float*)d_in[12];
  float* out = (float*)d_out;
  char* ws = (char*)d_ws;

  float* cn = (float*)(ws + OFF_CN);
  float* fn = (float*)(ws + OFF_FN);
  float* zn = (float*)(ws + OFF_ZN);
  float* rn = (float*)(ws + OFF_RN);
  float* lossp = (float*)(ws + OFF_LOSS);
  unsigned long long* amc = (unsigned long long*)(ws + OFF_AMC);
  unsigned long long* amf = (unsigned long long*)(ws + OFF_AMF);
  __hip_bfloat16* ceH = (__hip_bfloat16*)(ws + OFF_CEH);
  __hip_bfloat16* ceL = (__hip_bfloat16*)(ws + OFF_CEL);
  __hip_bfloat16* feH = (__hip_bfloat16*)(ws + OFF_FEH);
  __hip_bfloat16* feL = (__hip_bfloat16*)(ws + OFF_FEL);
  __hip_bfloat16* zcH = (__hip_bfloat16*)(ws + OFF_ZCH);
  __hip_bfloat16* zcL = (__hip_bfloat16*)(ws + OFF_ZCL);
  __hip_bfloat16* rH  = (__hip_bfloat16*)(ws + OFF_RH);
  __hip_bfloat16* rL  = (__hip_bfloat16*)(ws + OFF_RL);
  __hip_bfloat16* w1H = (__hip_bfloat16*)(ws + OFF_W1H);
  __hip_bfloat16* w1L = (__hip_bfloat16*)(ws + OFF_W1L);
  __hip_bfloat16* w2H = (__hip_bfloat16*)(ws + OFF_W2H);
  __hip_bfloat16* w2L = (__hip_bfloat16*)(ws + OFF_W2L);
  float* h = (float*)(ws + OFF_H);
  __hip_bfloat16* infl = (__hip_bfloat16*)(ws + OFF_INFL);

  // init argmin keys (coarse+fine contiguous) to u64 max
  hipMemsetAsync(ws + OFF_AMC, 0xFF, 131072, stream);

  // norms + splits (codebooks/weights -> frag, zc -> row-major); zero loss
  prep<<<5376, 256, 0, stream>>>(ce, fe, z, w_c2f, w_f2c, cn, fn, zn,
                                 ceH, ceL, feH, feL, zcH, zcL,
                                 w1H, w1L, w2H, w2L, lossp);

  // coarse VQ: 4096 codes x 8192 queries
  vq7<<<dim3(64, 16), 256, 0, stream>>>((const int4*)ceH, (const int4*)ceL,
                                        zcH, zcL, zn, cn, amc);

  // MLP1: h = gather(ce, amc) @ w_c2f^T + b
  mlp7<<<dim3(4, 64), 256, 0, stream>>>((const int4*)ceH, (const int4*)ceL, amc,
                                        (const int4*)w1H, (const int4*)w1L, b_c2f, h);

  // LN + leaky -> influence (bf16); residual hi/lo + norms
  ln_residual<<<8192, 256, 0, stream>>>(h, g_c2f, be_c2f, z, gcRaw, infl, rn, rH, rL);

  // fine VQ: 8192 codes x 8192 queries
  vq7<<<dim3(64, 32), 256, 0, stream>>>((const int4*)feH, (const int4*)feL,
                                        rH, rL, rn, fn, amf);

  // MLP2: h = gather(fe, amf) @ w_f2c^T + b
  mlp7<<<dim3(4, 64), 256, 0, stream>>>((const int4*)feH, (const int4*)feL, amf,
                                        (const int4*)w2H, (const int4*)w2L, b_f2c, h);

  // outputs + loss
  finalize<<<8192, 256, 0, stream>>>(h, g_f2c, be_f2c, infl, amc, amf, z, ce, fe,
                                     gcRaw, gfRaw, out, lossp);
  loss_write<<<1, 1, 0, stream>>>(lossp, out + (size_t)8192 * 1024);
}